// Round 1
// baseline (1643.901 us; speedup 1.0000x reference)
//
#include <hip/hip_runtime.h>

// ---------------- problem constants ----------------
#define NB 4
#define NC 17
#define T0 75000
#define NH 32
#define NK 8
// output: out[b*14336 + (o*NH + h)*NK + k], o = (di*2+diff)*2 + which(0=max,1=min)

// ---------------- kernel A: di 0..5 (d = 1..32), LDS-tiled ----------------
constexpr int TS = 1024;
constexpr int A_TILES = 74;                       // ceil(75000/1024)
constexpr int A_BLOCKS_PER_G = 128 * A_TILES;     // combos(b,h)=128
constexpr int A_GROUPS = 12;                      // di 0..5 x diff 0..1
constexpr int A_TOTAL_BLOCKS = A_GROUPS * A_BLOCKS_PER_G;  // 113664
constexpr int MAXSPAN = TS + 8 * 32;              // 1280

__global__ __launch_bounds__(256) void kernA(const float* __restrict__ X,
                                             const float* __restrict__ Wt,
                                             const int* __restrict__ idx,
                                             float* __restrict__ out) {
    __shared__ float Sbuf[MAXSPAN + 1];
    __shared__ float Dbuf[MAXSPAN];
    __shared__ float red[4][16];

    const int bid = blockIdx.x;
    const int ga   = bid / A_BLOCKS_PER_G;        // 0..11
    const int rem  = bid - ga * A_BLOCKS_PER_G;
    const int combo = rem / A_TILES;
    const int tile  = rem - combo * A_TILES;
    const int di = ga >> 1, diff = ga & 1;
    const int d = 1 << di;
    const int T = T0 - diff;
    const int b = combo >> 5, h = combo & 31;
    const int t0 = tile * TS;
    const int span = TS + 8 * d;
    const int tid = threadIdx.x;

    const int* ip = idx + ((di * 2 + diff) * NH + h) * 8;
    int offs[8];
#pragma unroll
    for (int i = 0; i < 8; ++i) offs[i] = (b * NC + ip[i]) * T0;

    // stage S = sum of 8 channels over [t0-4d, t0-4d+span] (span+1 elems)
    for (int ls = tid; ls <= span; ls += 256) {
        int u = t0 - 4 * d + ls;
        float s = 0.f;
        if (u >= 0 && u < T0) {
#pragma unroll
            for (int i = 0; i < 8; ++i) s += X[offs[i] + u];
        }
        Sbuf[ls] = s;
    }
    __syncthreads();
    const float* src = Sbuf;
    if (diff) {
        for (int ls = tid; ls < span; ls += 256) {
            int u = t0 - 4 * d + ls;
            Dbuf[ls] = (u >= 0 && u < T) ? (Sbuf[ls + 1] - Sbuf[ls]) : 0.f;
        }
        __syncthreads();
        src = Dbuf;
    }

    const float* wp = Wt + ((di * 2 + diff) * (NK * NH) + h * NK) * 9;
    float w[72];
#pragma unroll
    for (int i = 0; i < 72; ++i) w[i] = wp[i];

    float accM[8], accC[8];
#pragma unroll
    for (int k = 0; k < 8; ++k) { accM[k] = 0.f; accC[k] = 0.f; }

#pragma unroll
    for (int ii = 0; ii < 4; ++ii) {
        int pos = tid + ii * 256;
        int t = t0 + pos;
        if (t < T) {
            float z[8];
#pragma unroll
            for (int k = 0; k < 8; ++k) z[k] = 0.f;
#pragma unroll
            for (int j = 0; j < 9; ++j) {
                float g = src[pos + j * d];
#pragma unroll
                for (int k = 0; k < 8; ++k) z[k] = fmaf(w[k * 9 + j], g, z[k]);
            }
            float best = z[0], worst = z[0];
            int biK = 0, wiK = 0;
#pragma unroll
            for (int k = 1; k < 8; ++k) {
                if (z[k] > best)  { best = z[k];  biK = k; }
                if (z[k] < worst) { worst = z[k]; wiK = k; }
            }
#pragma unroll
            for (int k = 0; k < 8; ++k) {
                accM[k] += (k == biK) ? best : 0.f;
                accC[k] += (k == wiK) ? 1.f  : 0.f;
            }
        }
    }

    // wave butterfly reduce
#pragma unroll
    for (int k = 0; k < 8; ++k) {
#pragma unroll
        for (int sh = 1; sh < 64; sh <<= 1) {
            accM[k] += __shfl_xor(accM[k], sh, 64);
            accC[k] += __shfl_xor(accC[k], sh, 64);
        }
    }
    int wv = tid >> 6, lane = tid & 63;
    if (lane == 0) {
#pragma unroll
        for (int k = 0; k < 8; ++k) { red[wv][k] = accM[k]; red[wv][8 + k] = accC[k]; }
    }
    __syncthreads();
    if (tid < 16) {
        float v = red[0][tid] + red[1][tid] + red[2][tid] + red[3][tid];
        int which = tid >> 3;
        int k = tid & 7;
        int o = (di * 2 + diff) * 2 + which;
        atomicAdd(&out[(size_t)b * 14336 + (o * NH + h) * NK + k], v);
    }
}

// ---------------- kernel B: di 6..13 (d = 64..8192), register chains ----------------
struct BG { int base, segs, di, diff; };
constexpr BG BGS[16] = {
    {0,        1216,  6, 0}, {155648,  1216,  6, 1},
    {311296,   1280,  7, 0}, {475136,  1280,  7, 1},
    {638976,   1280,  8, 0}, {802816,  1280,  8, 1},
    {966656,   1536,  9, 0}, {1163264, 1536,  9, 1},
    {1359872,  2048, 10, 0}, {1622016, 2048, 10, 1},
    {1884160,  2048, 11, 0}, {2146304, 2048, 11, 1},
    {2408448,  4096, 12, 0}, {2932736, 4096, 12, 1},
    {3457024,  8192, 13, 0}, {4505600, 8192, 13, 1},
};
constexpr int B_TOTAL = 5554176;
constexpr int B_BLOCKS = B_TOTAL / 256;           // 21696 exact

__device__ __forceinline__ float gatherF(const float* __restrict__ X,
                                         const int* offs, int u, int T, int diffF) {
    float s = 0.f;
    if (u >= 0 && u < T) {
        float a0 = X[offs[0] + u], a1 = X[offs[1] + u];
        float a2 = X[offs[2] + u], a3 = X[offs[3] + u];
        float a4 = X[offs[4] + u], a5 = X[offs[5] + u];
        float a6 = X[offs[6] + u], a7 = X[offs[7] + u];
        s = ((a0 + a1) + (a2 + a3)) + ((a4 + a5) + (a6 + a7));
        if (diffF) {
            float b0 = X[offs[0] + u + 1], b1 = X[offs[1] + u + 1];
            float b2 = X[offs[2] + u + 1], b3 = X[offs[3] + u + 1];
            float b4 = X[offs[4] + u + 1], b5 = X[offs[5] + u + 1];
            float b6 = X[offs[6] + u + 1], b7 = X[offs[7] + u + 1];
            s = (((b0 + b1) + (b2 + b3)) + ((b4 + b5) + (b6 + b7))) - s;
        }
    }
    return s;
}

__global__ __launch_bounds__(256) void kernB(const float* __restrict__ X,
                                             const float* __restrict__ Wt,
                                             const int* __restrict__ idx,
                                             float* __restrict__ out) {
    const int gtid = blockIdx.x * 256 + threadIdx.x;

    int di = 0, diff = 0, r = 0, q0 = 0, combo = 0, Q = 1;
#pragma unroll
    for (int g = 0; g < 16; ++g) {
        const int base = BGS[g].base, segs = BGS[g].segs;
        const int gdi = BGS[g].di, gdiff = BGS[g].diff;
        const int gd = 1 << gdi;
        const int gT = T0 - gdiff;
        const int gQ = (gT + gd - 1) / gd;
        if (gtid >= base && gtid < base + 128 * segs) {
            int wgi = gtid - base;
            int c = wgi / segs;                    // compile-time magic div
            int s = wgi - c * segs;
            combo = c;
            q0 = (s >> gdi) * 63;
            r = s & (gd - 1);
            di = gdi; diff = gdiff; Q = gQ;
        }
    }
    // wave-uniform by construction (group bases, segs, d all multiples of 64)
    di    = __builtin_amdgcn_readfirstlane(di);
    diff  = __builtin_amdgcn_readfirstlane(diff);
    combo = __builtin_amdgcn_readfirstlane(combo);
    q0    = __builtin_amdgcn_readfirstlane(q0);
    Q     = __builtin_amdgcn_readfirstlane(Q);

    const int d = 1 << di;
    const int T = T0 - diff;
    const int b = combo >> 5, h = combo & 31;

    const int* ip = idx + ((di * 2 + diff) * NH + h) * 8;
    int offs[8];
#pragma unroll
    for (int i = 0; i < 8; ++i) offs[i] = (b * NC + ip[i]) * T0;

    const float* wp = Wt + ((di * 2 + diff) * (NK * NH) + h * NK) * 9;
    float w[72];
#pragma unroll
    for (int i = 0; i < 72; ++i) w[i] = wp[i];

    const int t0 = r + q0 * d;
    float buf[9];
#pragma unroll
    for (int j = 0; j < 9; ++j) buf[j] = gatherF(X, offs, t0 + (j - 4) * d, T, diff);

    float accM[8], accC[8];
#pragma unroll
    for (int k = 0; k < 8; ++k) { accM[k] = 0.f; accC[k] = 0.f; }

    for (int outer = 0; outer < 7; ++outer) {
        if (q0 + outer * 9 >= Q) break;
#pragma unroll
        for (int ii = 0; ii < 9; ++ii) {
            int i = outer * 9 + ii;
            int t = t0 + i * d;
            if (t < T) {
                float z[8];
#pragma unroll
                for (int k = 0; k < 8; ++k) z[k] = 0.f;
#pragma unroll
                for (int j = 0; j < 9; ++j) {
                    float g = buf[(ii + j) % 9];
#pragma unroll
                    for (int k = 0; k < 8; ++k) z[k] = fmaf(w[k * 9 + j], g, z[k]);
                }
                float best = z[0], worst = z[0];
                int biK = 0, wiK = 0;
#pragma unroll
                for (int k = 1; k < 8; ++k) {
                    if (z[k] > best)  { best = z[k];  biK = k; }
                    if (z[k] < worst) { worst = z[k]; wiK = k; }
                }
#pragma unroll
                for (int k = 0; k < 8; ++k) {
                    accM[k] += (k == biK) ? best : 0.f;
                    accC[k] += (k == wiK) ? 1.f  : 0.f;
                }
            }
            // slide window: buf[i%9] <- g(t + 5d)
            buf[ii] = gatherF(X, offs, t + 5 * d, T, diff);
        }
    }

    // wave butterfly reduce (all lanes same bins: combo wave-uniform)
#pragma unroll
    for (int k = 0; k < 8; ++k) {
#pragma unroll
        for (int sh = 1; sh < 64; sh <<= 1) {
            accM[k] += __shfl_xor(accM[k], sh, 64);
            accC[k] += __shfl_xor(accC[k], sh, 64);
        }
    }
    if ((threadIdx.x & 63) == 0) {
        int o = (di * 2 + diff) * 2;
        size_t bb = (size_t)b * 14336;
#pragma unroll
        for (int k = 0; k < 8; ++k) {
            atomicAdd(&out[bb + (o * NH + h) * NK + k],       accM[k]);
            atomicAdd(&out[bb + ((o + 1) * NH + h) * NK + k], accC[k]);
        }
    }
}

__global__ void zeroK(float* __restrict__ out, int n) {
    int i = blockIdx.x * 256 + threadIdx.x;
    if (i < n) out[i] = 0.f;
}

extern "C" void kernel_launch(void* const* d_in, const int* in_sizes, int n_in,
                              void* d_out, int out_size, void* d_ws, size_t ws_size,
                              hipStream_t stream) {
    const float* X  = (const float*)d_in[0];
    const float* Wt = (const float*)d_in[1];
    const int*  idx = (const int*)d_in[2];
    float* out = (float*)d_out;

    zeroK<<<(out_size + 255) / 256, 256, 0, stream>>>(out, out_size);
    kernA<<<A_TOTAL_BLOCKS, 256, 0, stream>>>(X, Wt, idx, out);
    kernB<<<B_BLOCKS, 256, 0, stream>>>(X, Wt, idx, out);
}